// Round 1
// baseline (6480.999 us; speedup 1.0000x reference)
//
#include <hip/hip_runtime.h>
#include <math.h>

#define NN 50000
#define NE 1600000
#define DD 128
#define NH 4
#define NC 32
#define HC 128
#define EDIM 64
#define NEG 0.2f

__device__ __forceinline__ unsigned fmap(float f) {
    unsigned b = __float_as_uint(f);
    return (b & 0x80000000u) ? ~b : (b | 0x80000000u);
}
__device__ __forceinline__ float funmap(unsigned u) {
    unsigned b = (u & 0x80000000u) ? (u ^ 0x80000000u) : ~u;
    return __uint_as_float(b);
}

// w_e[d*4+h] = sum_c We[d*128 + h*32 + c] * att_edge[h*32+c]
__global__ void k_we(const float* __restrict__ We, const float* __restrict__ att_edge,
                     float* __restrict__ w_e) {
    int t = threadIdx.x;            // 256 = 64*4
    int d = t >> 2, h = t & 3;
    float acc = 0.f;
    #pragma unroll
    for (int c = 0; c < NC; ++c) acc += We[d * HC + h * NC + c] * att_edge[h * NC + c];
    w_e[t] = acc;
}

__global__ void k_init(float* __restrict__ esum, unsigned* __restrict__ mu,
                       float* __restrict__ ssum, float* __restrict__ deg) {
    int i = blockIdx.x * blockDim.x + threadIdx.x;
    if (i < NN * NH) { esum[i] = 0.f; mu[i] = 0u; ssum[i] = 0.f; }
    if (i < NN) deg[i] = 0.f;
}

// one block (128 thr) per node: xp = x@W, a_src/a_dst shuffle-reduced
__global__ __launch_bounds__(128) void k_node1(
    const float* __restrict__ x, const float* __restrict__ W,
    const float* __restrict__ att_src, const float* __restrict__ att_dst,
    float* __restrict__ xp, float* __restrict__ a_src, float* __restrict__ a_dst) {
    __shared__ float xs[DD];
    int n = blockIdx.x;
    int t = threadIdx.x;
    xs[t] = x[(size_t)n * DD + t];
    __syncthreads();
    float acc = 0.f;
    #pragma unroll 8
    for (int d = 0; d < DD; ++d) acc += xs[d] * W[d * HC + t];
    xp[(size_t)n * HC + t] = acc;
    float ps = acc * att_src[t];
    float pd = acc * att_dst[t];
    #pragma unroll
    for (int off = 16; off; off >>= 1) {
        ps += __shfl_xor(ps, off, 32);
        pd += __shfl_xor(pd, off, 32);
    }
    if ((t & 31) == 0) {
        a_src[n * NH + (t >> 5)] = ps;
        a_dst[n * NH + (t >> 5)] = pd;
    }
}

// 16 lanes per edge: a_edge, alpha(leaky), esum/deg scatter, running max
__global__ __launch_bounds__(256) void k_edge1(
    const int* __restrict__ srcv, const int* __restrict__ dstv,
    const float* __restrict__ ea, const float* __restrict__ w_e,
    const float* __restrict__ a_src, const float* __restrict__ a_dst,
    float* __restrict__ esum, float* __restrict__ deg,
    unsigned* __restrict__ mu, float* __restrict__ ebuf) {
    __shared__ float swe[EDIM * NH];
    int t = threadIdx.x;
    swe[t] = w_e[t];
    __syncthreads();
    long long gid = (long long)blockIdx.x * 256 + t;
    int e = (int)(gid >> 4);
    if (e >= NE) return;
    int l = t & 15;
    int s = srcv[e], dnode = dstv[e];
    const float4* eap = (const float4*)(ea + (size_t)e * EDIM);
    float4 v = eap[l];
    float p0 = 0.f, p1 = 0.f, p2 = 0.f, p3 = 0.f;
    int d0 = l * 4;
    {
        float vals[4] = {v.x, v.y, v.z, v.w};
        #pragma unroll
        for (int j = 0; j < 4; ++j) {
            float a = vals[j];
            const float* wr = &swe[(d0 + j) * NH];
            p0 += a * wr[0]; p1 += a * wr[1]; p2 += a * wr[2]; p3 += a * wr[3];
        }
    }
    #pragma unroll
    for (int off = 8; off; off >>= 1) {
        p0 += __shfl_xor(p0, off, 16);
        p1 += __shfl_xor(p1, off, 16);
        p2 += __shfl_xor(p2, off, 16);
        p3 += __shfl_xor(p3, off, 16);
    }
    if (l < 4) {
        float aE = (l == 0) ? p0 : (l == 1) ? p1 : (l == 2) ? p2 : p3;
        atomicAdd(&esum[dnode * NH + l], aE);
        float al = a_src[s * NH + l] + a_dst[dnode * NH + l] + aE;
        al = (al >= 0.f) ? al : NEG * al;
        ebuf[(size_t)e * NH + l] = al;
        atomicMax(&mu[dnode * NH + l], fmap(al));
    } else if (l == 4) {
        atomicAdd(&deg[dnode], 1.0f);
    }
}

// per (node,head): self-loop alpha, final max, seed denominator
__global__ void k_node2(const float* __restrict__ a_src, const float* __restrict__ a_dst,
                        const float* __restrict__ esum, const float* __restrict__ deg,
                        unsigned* __restrict__ mu, float* __restrict__ ssum,
                        float* __restrict__ exself) {
    int i = blockIdx.x * blockDim.x + threadIdx.x;
    if (i >= NN * NH) return;
    int n = i >> 2;
    float dg = fmaxf(deg[n], 1.0f);
    float al = a_src[i] + a_dst[i] + esum[i] / dg;
    al = (al >= 0.f) ? al : NEG * al;
    unsigned u = mu[i];
    float mf = (u == 0u) ? -INFINITY : funmap(u);
    float m = fmaxf(mf, al);
    ((float*)mu)[i] = m;            // overwrite with float max
    float ex = __expf(al - m);
    exself[i] = ex;
    ssum[i] = ex;
}

// per (edge,head): ex = exp(alpha-m), accumulate denominator
__global__ void k_edge2(const int* __restrict__ dstv, const float* __restrict__ mbuf,
                        float* __restrict__ ebuf, float* __restrict__ ssum) {
    long long gid = (long long)blockIdx.x * blockDim.x + threadIdx.x;
    if (gid >= (long long)NE * NH) return;
    int e = (int)(gid >> 2), h = (int)(gid & 3);
    int dnode = dstv[e];
    float al = ebuf[gid];
    float ex = __expf(al - mbuf[dnode * NH + h]);
    ebuf[gid] = ex;
    atomicAdd(&ssum[dnode * NH + h], ex);
}

// per (node,channel): out = attn_self * xp + bias  (full overwrite of d_out)
__global__ void k_node3(const float* __restrict__ xp, const float* __restrict__ ssum,
                        const float* __restrict__ exself, const float* __restrict__ bias,
                        float* __restrict__ out) {
    int i = blockIdx.x * blockDim.x + threadIdx.x;
    if (i >= NN * HC) return;
    int n = i >> 7, t = i & 127, h = t >> 5;
    float inv = 1.0f / (ssum[n * NH + h] + 1e-16f);
    float at = exself[n * NH + h] * inv;
    out[i] = at * xp[i] + bias[t];
}

// 16 lanes per edge, 8 channels each: scatter attn * xp[src] into out[dst]
__global__ __launch_bounds__(256) void k_edge3(
    const int* __restrict__ srcv, const int* __restrict__ dstv,
    const float* __restrict__ xp, const float* __restrict__ ebuf,
    const float* __restrict__ ssum, float* __restrict__ out) {
    long long gid = (long long)blockIdx.x * 256 + threadIdx.x;
    int e = (int)(gid >> 4);
    if (e >= NE) return;
    int l = (int)(gid & 15);
    int h = l >> 2;
    int s = srcv[e], dnode = dstv[e];
    float at = ebuf[(size_t)e * NH + h] / (ssum[dnode * NH + h] + 1e-16f);
    const float4* xs = (const float4*)(xp + (size_t)s * HC + l * 8);
    float4 v0 = xs[0], v1 = xs[1];
    float* ob = out + (size_t)dnode * HC + l * 8;
    atomicAdd(ob + 0, at * v0.x); atomicAdd(ob + 1, at * v0.y);
    atomicAdd(ob + 2, at * v0.z); atomicAdd(ob + 3, at * v0.w);
    atomicAdd(ob + 4, at * v1.x); atomicAdd(ob + 5, at * v1.y);
    atomicAdd(ob + 6, at * v1.z); atomicAdd(ob + 7, at * v1.w);
}

extern "C" void kernel_launch(void* const* d_in, const int* in_sizes, int n_in,
                              void* d_out, int out_size, void* d_ws, size_t ws_size,
                              hipStream_t stream) {
    const float* x        = (const float*)d_in[0];
    const int*   ei       = (const int*)d_in[1];
    const float* ea       = (const float*)d_in[2];
    const float* W        = (const float*)d_in[3];
    const float* att_src  = (const float*)d_in[4];
    const float* att_dst  = (const float*)d_in[5];
    const float* We       = (const float*)d_in[6];
    const float* att_edge = (const float*)d_in[7];
    const float* bias     = (const float*)d_in[8];
    float* out = (float*)d_out;

    float* ws = (float*)d_ws;
    float* xp     = ws;                                  // N*128
    float* a_src  = xp + (size_t)NN * HC;                // N*4
    float* a_dst  = a_src + (size_t)NN * NH;
    float* esum   = a_dst + (size_t)NN * NH;
    float* mbuf   = esum + (size_t)NN * NH;              // uint max -> float max
    float* ssum   = mbuf + (size_t)NN * NH;
    float* exself = ssum + (size_t)NN * NH;
    float* deg    = exself + (size_t)NN * NH;            // N
    float* ebuf   = deg + (size_t)NN;                    // E*4
    float* w_e    = ebuf + (size_t)NE * NH;              // 256

    const int* srcv = ei;
    const int* dstv = ei + NE;

    k_we<<<1, 256, 0, stream>>>(We, att_edge, w_e);
    k_init<<<(NN * NH + 255) / 256, 256, 0, stream>>>(esum, (unsigned*)mbuf, ssum, deg);
    k_node1<<<NN, 128, 0, stream>>>(x, W, att_src, att_dst, xp, a_src, a_dst);
    k_edge1<<<(NE * 16) / 256, 256, 0, stream>>>(srcv, dstv, ea, w_e, a_src, a_dst,
                                                 esum, deg, (unsigned*)mbuf, ebuf);
    k_node2<<<(NN * NH + 255) / 256, 256, 0, stream>>>(a_src, a_dst, esum, deg,
                                                       (unsigned*)mbuf, ssum, exself);
    k_edge2<<<(NE * NH) / 256, 256, 0, stream>>>(dstv, mbuf, ebuf, ssum);
    k_node3<<<(NN * HC) / 256, 256, 0, stream>>>(xp, ssum, exself, bias, out);
    k_edge3<<<(NE * 16) / 256, 256, 0, stream>>>(srcv, dstv, xp, ebuf, ssum, out);
}